// Round 6
// baseline (331.684 us; speedup 1.0000x reference)
//
#include <hip/hip_runtime.h>

#define NIB_SCALE 100.0f

// ---- DPP helpers (16-lane "row" ops on the VALU pipe; rows == nibble groups) ----
// ctrl: 0x110+N row_shr, 0x120+N row_ror, 0x140 row_mirror
template<int CTRL>
__device__ __forceinline__ float fdpp(float x) {
    return __int_as_float(__builtin_amdgcn_update_dpp(
        0, __float_as_int(x), CTRL, 0xF, 0xF, true));
}

__device__ __forceinline__ float rsum16d(float v) {
    v += fdpp<0x121>(v); v += fdpp<0x122>(v); v += fdpp<0x124>(v); v += fdpp<0x128>(v);
    return v;
}
__device__ __forceinline__ float rmax16d(float v) {
    v = fmaxf(v, fdpp<0x121>(v)); v = fmaxf(v, fdpp<0x122>(v));
    v = fmaxf(v, fdpp<0x124>(v)); v = fmaxf(v, fdpp<0x128>(v));
    return v;
}
// inclusive ascending prefix sum within the 16-lane row
__device__ __forceinline__ float scan16d(float v) {
    v += fdpp<0x111>(v); v += fdpp<0x112>(v); v += fdpp<0x114>(v); v += fdpp<0x118>(v);
    return v;
}
__device__ __forceinline__ float softmax16d(float v) {
    float m = rmax16d(v);
    float e = __expf(NIB_SCALE * (v - m));
    float s = rsum16d(e);
    return e / s;
}
// for inputs known to lie in [0,1] with row-sum 1 (max >= 1/16): a FIXED shift
// of 0.5 keeps exponents in [-50,50] (no overflow/underflow, ratios exact) and
// removes the 8-inst DPP max chain from the critical path.
__device__ __forceinline__ float softmax16_fix(float v) {
    float e = __expf(NIB_SCALE * (v - 0.5f));
    float s = rsum16d(e);
    return e / s;
}
__device__ __forceinline__ float sharp_sigmoid(float c) {
    // softmax2(100*[1-c, c])[1] = 1/(1+exp(100*(1-2c)))
    return 1.0f / (1.0f + __expf(NIB_SCALE * (1.0f - 2.0f * c)));
}
__device__ __forceinline__ float rdlane(float x, int l) {
    return __int_as_float(__builtin_amdgcn_readlane(__float_as_int(x), l));
}

// one quarter of the circular conv: 4-FMA chain over one float4 of Q with
// in-place rotated P values (no G[] array -> shorter chains, fewer live regs)
__device__ __forceinline__ float conv_quad(float g0, float g1, float g2, float g3,
                                           const float4 q) {
    return fmaf(g0, q.x, fmaf(g1, q.y, fmaf(g2, q.z, g3 * q.w)));
}

// Full per-row tail after the four logits are known. All cross-lane traffic is
// intra-wave (DPP / readlane / LDS broadcast reads) -> no barriers.
__device__ __forceinline__ void stream_tail(float al, float bl, float ah, float bh,
                                            int k, int g, int b,
                                            float (&QL)[16][16], float (&QH)[16][16],
                                            float (&PSL)[16][16], float (&PSH)[16][16],
                                            float* __restrict__ po) {
    // factorized sharp softmaxes (exact vs the joint 512-softmax)
    float pal = softmax16d(al);
    float pbl = softmax16d(bl);
    float pah = softmax16d(ah);
    float pbh = softmax16d(bh);

    QL[g][k] = pbl;
    QH[g][k] = pbh;

    // overflow masses, pure DPP:
    // mir[k]=q[15-k]; T15[k]=sum_{v>=15-k} q[v]; ov15=sum_{a+v>=15} p[a]q[v]
    float mirl = fdpp<0x140>(pbl);
    float mirh = fdpp<0x140>(pbh);
    float T15l = scan16d(mirl);
    float T15h = scan16d(mirh);
    float ov15l = rsum16d(pal * T15l);
    float c15l  = rsum16d(pal * mirl);
    float ov15h = rsum16d(pah * T15h);
    float c15h  = rsum16d(pah * mirh);
    float ov16l = ov15l - c15l;
    float ov16h = ov15h - c15h;

    // wave-level broadcast of the per-byte carry masses via readlane (bytes
    // 0..3 live in wave-lanes 0/16/32/48) -- replaces the LDS sOV
    // write->wait->read roundtrip that sat on the serial carry path.
    float l16[4] = { rdlane(ov16l,0), rdlane(ov16l,16), rdlane(ov16l,32), rdlane(ov16l,48) };
    float l15[4] = { rdlane(ov15l,0), rdlane(ov15l,16), rdlane(ov15l,32), rdlane(ov15l,48) };
    float h16[4] = { rdlane(ov16h,0), rdlane(ov16h,16), rdlane(ov16h,32), rdlane(ov16h,48) };
    float h15[4] = { rdlane(ov15h,0), rdlane(ov15h,16), rdlane(ov15h,32), rdlane(ov15h,48) };

    // ---- circular convolutions r[k] = sum_j p[(k-j)&15] q[j] ----
    // independent of the carry chain below; scheduler interleaves the two.
    const float4 La = *(const float4*)&QL[g][0];
    const float4 Lb = *(const float4*)&QL[g][4];
    const float4 Lc = *(const float4*)&QL[g][8];
    const float4 Ld = *(const float4*)&QL[g][12];
    float rl = (conv_quad(pal,              fdpp<0x121>(pal), fdpp<0x122>(pal), fdpp<0x123>(pal), La)
              + conv_quad(fdpp<0x124>(pal), fdpp<0x125>(pal), fdpp<0x126>(pal), fdpp<0x127>(pal), Lb))
             + (conv_quad(fdpp<0x128>(pal), fdpp<0x129>(pal), fdpp<0x12A>(pal), fdpp<0x12B>(pal), Lc)
              + conv_quad(fdpp<0x12C>(pal), fdpp<0x12D>(pal), fdpp<0x12E>(pal), fdpp<0x12F>(pal), Ld));

    const float4 Ha = *(const float4*)&QH[g][0];
    const float4 Hb = *(const float4*)&QH[g][4];
    const float4 Hc = *(const float4*)&QH[g][8];
    const float4 Hd = *(const float4*)&QH[g][12];
    float rh = (conv_quad(pah,              fdpp<0x121>(pah), fdpp<0x122>(pah), fdpp<0x123>(pah), Ha)
              + conv_quad(fdpp<0x124>(pah), fdpp<0x125>(pah), fdpp<0x126>(pah), fdpp<0x127>(pah), Hb))
             + (conv_quad(fdpp<0x128>(pah), fdpp<0x129>(pah), fdpp<0x12A>(pah), fdpp<0x12B>(pah), Hc)
              + conv_quad(fdpp<0x12C>(pah), fdpp<0x12D>(pah), fdpp<0x12E>(pah), fdpp<0x12F>(pah), Hd));

    // ---- serial carry chain (tiny; redundantly computed by every lane) ----
    // byte 0: incoming pc = (1, 0)  (softmax2([1,0]*100): pc1 = 3.7e-44 ~ 0)
    float qc1_0 = sharp_sigmoid(l16[0]);
    float qc0_0 = 1.f - qc1_0;
    float pc1_1 = sharp_sigmoid(qc0_0 * h16[0] + qc1_0 * h15[0]);
    float pc0_1 = 1.f - pc1_1;
    float qc1_1 = sharp_sigmoid(pc0_1 * l16[1] + pc1_1 * l15[1]);
    float qc0_1 = 1.f - qc1_1;
    float pc1_2 = sharp_sigmoid(qc0_1 * h16[1] + qc1_1 * h15[1]);
    float pc0_2 = 1.f - pc1_2;
    float qc1_2 = sharp_sigmoid(pc0_2 * l16[2] + pc1_2 * l15[2]);
    float qc0_2 = 1.f - qc1_2;
    float pc1_3 = sharp_sigmoid(qc0_2 * h16[2] + qc1_2 * h15[2]);
    float pc0_3 = 1.f - pc1_3;
    float qc1_3 = sharp_sigmoid(pc0_3 * l16[3] + pc1_3 * l15[3]);
    float qc0_3 = 1.f - qc1_3;

    // select this group's byte position (b is group-uniform -> cheap cndmasks)
    float pc0 = b == 0 ? 1.f   : b == 1 ? pc0_1 : b == 2 ? pc0_2 : pc0_3;
    float pc1 = b == 0 ? 0.f   : b == 1 ? pc1_1 : b == 2 ? pc1_2 : pc1_3;
    float qc0 = b == 0 ? qc0_0 : b == 1 ? qc0_1 : b == 2 ? qc0_2 : qc0_3;
    float qc1 = b == 0 ? qc1_0 : b == 1 ? qc1_1 : b == 2 ? qc1_2 : qc1_3;

    // ---- nibble sums with carry mixing ----
    float slow  = pc0 * rl + pc1 * fdpp<0x121>(rl);   // rl[(k-1)&15]
    float shigh = qc0 * rh + qc1 * fdpp<0x121>(rh);

    // ---- n2b: out[16h + l] = psh[h] * psl[l] ----
    float psl = softmax16_fix(slow);
    float psh = softmax16_fix(shigh);
    PSL[g][k] = psl;
    PSH[g][k] = psh;

    // full-cache-line stores: instr c writes group's bytes [64c .. 64c+63]
    const float4 pslq = *(const float4*)&PSL[g][4 * (k & 3)];
    #pragma unroll
    for (int c = 0; c < 4; ++c) {
        float hs = PSH[g][4 * c + (k >> 2)];
        *(float4*)(po + 64 * c + 4 * k) =
            make_float4(hs * pslq.x, hs * pslq.y, hs * pslq.z, hs * pslq.w);
    }
}

// TWO rows per wave as two independent dataflow streams + FULL occupancy.
// r5 proved this code fits 64 VGPR spill-free (WRITE_SIZE clean) but was
// self-capped to 4 waves/EU. launch_bounds(256, 8) requires the 64-VGPR
// allocation (8 waves/EU) the compiler already chose, doubling resident
// contexts to 16 streams/SIMD. Canaries: VGPR must stay 64, WRITE_SIZE
// must stay 131072 KB.
__global__ __launch_bounds__(256, 8)
void nalu_kernel(const float* __restrict__ A,
                 const float* __restrict__ B,
                 float* __restrict__ O,
                 int nrows) {
    __shared__ __align__(16) float sQL[2][16][16];
    __shared__ __align__(16) float sQH[2][16][16];
    __shared__ __align__(16) float sPSL[2][16][16];
    __shared__ __align__(16) float sPSH[2][16][16];

    const int tid = threadIdx.x;
    const int k = tid & 15;           // nibble-value lane within the 16-lane group
    const int g = tid >> 4;           // group id within block (16 groups)
    const int b = g & 3;              // byte index handled by this group
    const int w = tid >> 6;           // wave id within block
    const int row0 = blockIdx.x * 8 + w * 2;
    if (row0 >= nrows) return;        // wave-uniform
    const long base0 = (long)row0 * 1024 + b * 256;
    // tail clamp: stream 1 duplicates stream 0 (same data, same address, benign)
    const long base1 = base0 + ((row0 + 1 < nrows) ? 1024 : 0);

    const float* pa0 = A + base0;  const float* pb0 = B + base0;
    const float* pa1 = A + base1;  const float* pb1 = B + base1;

    // ---- both streams' row loads first: 16 float4 in flight ----
    const float4* qa0 = (const float4*)(pa0 + 16 * k);
    const float4* qb0 = (const float4*)(pb0 + 16 * k);
    const float4* qa1 = (const float4*)(pa1 + 16 * k);
    const float4* qb1 = (const float4*)(pb1 + 16 * k);
    float4 ra0 = qa0[0], ra1 = qa0[1], ra2 = qa0[2], ra3 = qa0[3];
    float4 rb0 = qb0[0], rb1 = qb0[1], rb2 = qb0[2], rb3 = qb0[3];
    float4 sa0 = qa1[0], sa1 = qa1[1], sa2 = qa1[2], sa3 = qa1[3];
    float4 sb0 = qb1[0], sb1 = qb1[1], sb2 = qb1[2], sb3 = qb1[3];

    // ---- s0 column loads (low-nibble logits): strided dwords, accumulated ----
    float uA0 = 0, uA1 = 0, uA2 = 0, uA3 = 0, uB0 = 0, uB1 = 0, uB2 = 0, uB3 = 0;
    #pragma unroll
    for (int e = 0; e < 4; ++e) {
        uA0 += pa0[16 * e + k];        uB0 += pb0[16 * e + k];
        uA1 += pa0[16 * (e + 4) + k];  uB1 += pb0[16 * (e + 4) + k];
        uA2 += pa0[16 * (e + 8) + k];  uB2 += pb0[16 * (e + 8) + k];
        uA3 += pa0[16 * (e + 12) + k]; uB3 += pb0[16 * (e + 12) + k];
    }

    // ---- consume s0 (frees its 32 row regs + col temps) ----
    float al0 = (uA0 + uA1) + (uA2 + uA3);
    float bl0 = (uB0 + uB1) + (uB2 + uB3);
    float ah0 = ((ra0.x + ra0.y) + (ra0.z + ra0.w)) + ((ra1.x + ra1.y) + (ra1.z + ra1.w))
              + ((ra2.x + ra2.y) + (ra2.z + ra2.w)) + ((ra3.x + ra3.y) + (ra3.z + ra3.w));
    float bh0 = ((rb0.x + rb0.y) + (rb0.z + rb0.w)) + ((rb1.x + rb1.y) + (rb1.z + rb1.w))
              + ((rb2.x + rb2.y) + (rb2.z + rb2.w)) + ((rb3.x + rb3.y) + (rb3.z + rb3.w));

    // ---- s1 column loads: issued here so their latency hides under tail0 ----
    float vA0 = 0, vA1 = 0, vA2 = 0, vA3 = 0, vB0 = 0, vB1 = 0, vB2 = 0, vB3 = 0;
    #pragma unroll
    for (int e = 0; e < 4; ++e) {
        vA0 += pa1[16 * e + k];        vB0 += pb1[16 * e + k];
        vA1 += pa1[16 * (e + 4) + k];  vB1 += pb1[16 * (e + 4) + k];
        vA2 += pa1[16 * (e + 8) + k];  vB2 += pb1[16 * (e + 8) + k];
        vA3 += pa1[16 * (e + 12) + k]; vB3 += pb1[16 * (e + 12) + k];
    }

    // pin all loads above the compute tails
    __builtin_amdgcn_sched_barrier(0);

    // ---- stream 0 tail (s1 loads landing underneath) ----
    stream_tail(al0, bl0, ah0, bh0, k, g, b, sQL[0], sQH[0], sPSL[0], sPSH[0], O + base0);

    // ---- consume s1 ----
    float al1 = (vA0 + vA1) + (vA2 + vA3);
    float bl1 = (vB0 + vB1) + (vB2 + vB3);
    float ah1 = ((sa0.x + sa0.y) + (sa0.z + sa0.w)) + ((sa1.x + sa1.y) + (sa1.z + sa1.w))
              + ((sa2.x + sa2.y) + (sa2.z + sa2.w)) + ((sa3.x + sa3.y) + (sa3.z + sa3.w));
    float bh1 = ((sb0.x + sb0.y) + (sb0.z + sb0.w)) + ((sb1.x + sb1.y) + (sb1.z + sb1.w))
              + ((sb2.x + sb2.y) + (sb2.z + sb2.w)) + ((sb3.x + sb3.y) + (sb3.z + sb3.w));

    // ---- stream 1 tail (scheduler interleaves with remnants of tail0) ----
    stream_tail(al1, bl1, ah1, bh1, k, g, b, sQL[1], sQH[1], sPSL[1], sPSH[1], O + base1);
}

extern "C" void kernel_launch(void* const* d_in, const int* in_sizes, int n_in,
                              void* d_out, int out_size, void* d_ws, size_t ws_size,
                              hipStream_t stream) {
    const float* A = (const float*)d_in[0];
    const float* B = (const float*)d_in[1];
    float* O = (float*)d_out;
    int nrows = in_sizes[0] / 1024;          // [B,4,256] -> B
    int grid = (nrows + 7) / 8;              // 8 rows per block: 4 waves x 2 streams
    nalu_kernel<<<grid, 256, 0, stream>>>(A, B, O, nrows);
}